// Round 15
// baseline (466.773 us; speedup 1.0000x reference)
//
#include <hip/hip_runtime.h>
#include <stdint.h>

// Problem constants: B=128, CAP=65536, H=512, NH=8, HD=64, GH=128
// Outputs (f32): memory_output[128*512] | new_usage[65536] | new_last[65536]

typedef __bf16 b16x8 __attribute__((ext_vector_type(8)));
typedef float f32x4 __attribute__((ext_vector_type(4)));

static __device__ __forceinline__ unsigned short f2bf(float f) {
  return __builtin_bit_cast(unsigned short, (__bf16)f);   // compiler emits v_cvt_pk_bf16_f32
}

static __device__ __forceinline__ f32x4 MFMA(b16x8 a, b16x8 b, f32x4 c) {
  return __builtin_amdgcn_mfma_f32_16x16x32_bf16(a, b, c, 0, 0, 0);
}

#define SBAR() __builtin_amdgcn_sched_barrier(0)

// ---------------------------------------------------------------------------
// 1) convert wk,wv (in_proj_w rows 512..1535) fp32 -> bf16, contiguous dest
__global__ void k_convert_w(const float* __restrict__ w, unsigned short* __restrict__ dst) {
  int i = blockIdx.x * 256 + threadIdx.x;              // 131072 threads x 4 elems
  float4 v = reinterpret_cast<const float4*>(w + 512 * 512)[i];
  ushort4 o;
  o.x = f2bf(v.x); o.y = f2bf(v.y); o.z = f2bf(v.z); o.w = f2bf(v.w);
  reinterpret_cast<ushort4*>(dst)[i] = o;
}

// ---------------------------------------------------------------------------
// 2) q projection: q[b][j] = query[b,:]·wq[j,:] + bq[j]  (fp32 dot, bf16 out)
__global__ void k_proj_q(const float* __restrict__ query, const float* __restrict__ w,
                         const float* __restrict__ bias, unsigned short* __restrict__ qout) {
  __shared__ float qs[512];
  int b = blockIdx.x, j = threadIdx.x;                 // 512 threads
  qs[j] = query[b * 512 + j];
  __syncthreads();
  float acc = bias[j];
  const float4* q4 = reinterpret_cast<const float4*>(qs);
  const float4* w4 = reinterpret_cast<const float4*>(w + j * 512);
#pragma unroll 8
  for (int i = 0; i < 128; ++i) {
    float4 a = q4[i], c = w4[i];
    acc += a.x * c.x + a.y * c.y + a.z * c.z + a.w * c.w;
  }
  qout[b * 512 + j] = f2bf(acc);
}

// ---------------------------------------------------------------------------
// 3) gate[b] = sigmoid(relu(query·gw1^T + gb1)·gw2^T + gb2)
__global__ void k_gate(const float* __restrict__ query, const float* __restrict__ w1,
                       const float* __restrict__ b1, const float* __restrict__ w2,
                       const float* __restrict__ b2, float* __restrict__ gate) {
  __shared__ float qs[512];
  __shared__ float red[2];
  int b = blockIdx.x, j = threadIdx.x;                 // 128 threads
  qs[j] = query[b * 512 + j];
  qs[j + 128] = query[b * 512 + j + 128];
  qs[j + 256] = query[b * 512 + j + 256];
  qs[j + 384] = query[b * 512 + j + 384];
  __syncthreads();
  float acc = b1[j];
  const float4* q4 = reinterpret_cast<const float4*>(qs);
  const float4* w4 = reinterpret_cast<const float4*>(w1 + j * 512);
#pragma unroll 8
  for (int i = 0; i < 128; ++i) {
    float4 a = q4[i], c = w4[i];
    acc += a.x * c.x + a.y * c.y + a.z * c.z + a.w * c.w;
  }
  float t = fmaxf(acc, 0.f) * w2[j];
#pragma unroll
  for (int off = 1; off < 64; off <<= 1) t += __shfl_xor(t, off, 64);
  if ((j & 63) == 0) red[j >> 6] = t;
  __syncthreads();
  if (j == 0) {
    float z = red[0] + red[1] + b2[0];
    gate[b] = 1.f / (1.f + __builtin_amdgcn_exp2f(-z * 1.44269504088896f));
  }
}

// ---------------------------------------------------------------------------
// 4) K/V projection GEMMs — A-RESIDENT BM=64 + W-IN-REGISTERS, NO in-loop
//    barriers/waits. A (64 x 512 bf16, chunk^(row&7)) staged once: 64 KB LDS,
//    one __syncthreads. Per j-tile each thread loads its OWN W fragments
//    (2 rows x 512 K = 32 x uint4) straight from global (L2-hot, order pinned
//    by sched_barrier in 4 chunk-groups); the compiler's dependency-driven
//    counted vmcnt drains each chunk when its MFMAs need it (up to 24 loads
//    in flight). Waves fully decoupled -> no lockstep barrier cost.
//    512 thr / 8 waves, wave grid 2(c) x 4(j), acc[2][2]; 2 blocks/CU.
__global__ __launch_bounds__(512, 4) void k_proj_kv(
    const float* __restrict__ mk, const float* __restrict__ mv,
    const unsigned short* __restrict__ wkb, const unsigned short* __restrict__ wvb,
    const float* __restrict__ in_b,
    unsigned short* __restrict__ kout, unsigned short* __restrict__ vtout) {
  const int p = blockIdx.x;                            // 2048 blocks
  const int isV = p & 1;
  const int c0 = (p >> 1) * 64;
  const float* Ag = isV ? mv : mk;
  const unsigned short* W = isV ? wvb : wkb;
  const float* bias = in_b + (isV ? 1024 : 512);
  const int tid = threadIdx.x;
  const int w = tid >> 6, lane = tid & 63;
  const int wr = w >> 2, wc = w & 3;                   // wave grid 2 (c) x 4 (j)
  const int ln = tid & 15, g = (tid & 63) >> 4;

  __shared__ __align__(16) unsigned short AL[32768];   // 64 KB [64][512] bf16 swz

  // --- A-stage: 8 iters, wave w reads full 2-KB row (c*8+w), cvt, swz write
#pragma unroll 4
  for (int c = 0; c < 8; ++c) {
    int row = c * 8 + w;
    const float* src = Ag + (size_t)(c0 + row) * 512 + lane * 8;
    float4 f0 = *reinterpret_cast<const float4*>(src);
    float4 f1 = *reinterpret_cast<const float4*>(src + 4);
    b16x8 v;
    v[0] = (__bf16)f0.x; v[1] = (__bf16)f0.y; v[2] = (__bf16)f0.z; v[3] = (__bf16)f0.w;
    v[4] = (__bf16)f1.x; v[5] = (__bf16)f1.y; v[6] = (__bf16)f1.z; v[7] = (__bf16)f1.w;
    int chunk = lane ^ (row & 7);                      // 16-B chunk swizzle
    *reinterpret_cast<b16x8*>(&AL[row * 512 + chunk * 8]) = v;
  }
  __syncthreads();                                     // ONLY block-wide sync

  // thread's W fragment base: row j0 + 32*wc + ln (+16 for n=1), cols +g*8
  const unsigned short* wbase = W + (size_t)(32 * wc + ln) * 512 + g * 8;

  // --- main: 4 j-tiles; per tile: 32 reg-loads of W, 64 MFMA, 0 barriers ---
#pragma unroll
  for (int jt = 0; jt < 4; ++jt) {
    const unsigned short* wb0 = wbase + (size_t)jt * 128 * 512;  // n=0 row
    const unsigned short* wb1 = wb0 + 16 * 512;                  // n=1 row
    uint4 wreg[4][2][4];                               // [chunk][n][ks] static idx
#pragma unroll
    for (int kc = 0; kc < 4; ++kc) {
#pragma unroll
      for (int ks = 0; ks < 4; ++ks) {
        wreg[kc][0][ks] = *reinterpret_cast<const uint4*>(wb0 + kc * 128 + ks * 32);
        wreg[kc][1][ks] = *reinterpret_cast<const uint4*>(wb1 + kc * 128 + ks * 32);
      }
      SBAR();                                          // pin chunk issue order
    }

    f32x4 acc[2][2];
#pragma unroll
    for (int m = 0; m < 2; ++m)
#pragma unroll
      for (int n = 0; n < 2; ++n) acc[m][n] = {0.f, 0.f, 0.f, 0.f};

#pragma unroll
    for (int kc = 0; kc < 4; ++kc) {
#pragma unroll
      for (int ks = 0; ks < 4; ++ks) {
        const int kk = kc * 4 + ks;
        b16x8 af[2];
#pragma unroll
        for (int m = 0; m < 2; ++m) {
          int r = 32 * wr + 16 * m + ln;
          int ch = (kk * 4 + g) ^ (r & 7);
          af[m] = *reinterpret_cast<const b16x8*>(&AL[r * 512 + ch * 8]);
        }
        b16x8 wf0 = __builtin_bit_cast(b16x8, wreg[kc][0][ks]);
        b16x8 wf1 = __builtin_bit_cast(b16x8, wreg[kc][1][ks]);
        if (!isV) {
#pragma unroll
          for (int m = 0; m < 2; ++m) {
            acc[m][0] = MFMA(wf0, af[m], acc[m][0]);
            acc[m][1] = MFMA(wf1, af[m], acc[m][1]);
          }
        } else {
#pragma unroll
          for (int m = 0; m < 2; ++m) {
            acc[m][0] = MFMA(af[m], wf0, acc[m][0]);
            acc[m][1] = MFMA(af[m], wf1, acc[m][1]);
          }
        }
      }
    }

    // epilogue for this j-tile (R13/R14-verified mapping)
    const int j0 = jt * 128;
    if (!isV) {
#pragma unroll
      for (int m = 0; m < 2; ++m) {
        int c = c0 + 32 * wr + 16 * m + ln;
#pragma unroll
        for (int n = 0; n < 2; ++n) {
          int jb = j0 + 32 * wc + 16 * n + 4 * g;
          float4 bb = *reinterpret_cast<const float4*>(&bias[jb]);
          ushort4 o;
          o.x = f2bf(acc[m][n][0] + bb.x);
          o.y = f2bf(acc[m][n][1] + bb.y);
          o.z = f2bf(acc[m][n][2] + bb.z);
          o.w = f2bf(acc[m][n][3] + bb.w);
          *reinterpret_cast<ushort4*>(&kout[(size_t)c * 512 + jb]) = o;
        }
      }
    } else {
#pragma unroll
      for (int n = 0; n < 2; ++n) {
        int j = j0 + 32 * wc + 16 * n + ln;
        float bj = bias[j];
#pragma unroll
        for (int m = 0; m < 2; ++m) {
          int cb = c0 + 32 * wr + 16 * m + 4 * g;
          ushort4 o;
          o.x = f2bf(acc[m][n][0] + bj);
          o.y = f2bf(acc[m][n][1] + bj);
          o.z = f2bf(acc[m][n][2] + bj);
          o.w = f2bf(acc[m][n][3] + bj);
          *reinterpret_cast<ushort4*>(&vtout[(size_t)j * 65536 + cb]) = o;
        }
      }
    }
  }
}

// ---------------------------------------------------------------------------
// 5) attn1: per (head, c-group of 1024): sT = k·q^T (swapped QK^T), p=exp2(s*SC),
//    l[b,h] += row sums; ctxT[h*64+d][b] += sum_c p·vT  (unnormalized)
__global__ __launch_bounds__(256) void k_attn1(
    const unsigned short* __restrict__ kb, const unsigned short* __restrict__ vt,
    const unsigned short* __restrict__ qb,
    float* __restrict__ l_ws, float* __restrict__ ctxT) {
  const int h = blockIdx.y, cg = blockIdx.x;
  const int tid = threadIdx.x;
  const int wv = tid >> 6, wr = wv >> 1, wc = wv & 1;
  const int ln = tid & 15, g = (tid & 63) >> 4;
  __shared__ __align__(16) unsigned short kS[128 * 64];
  __shared__ __align__(16) unsigned short pS[128 * 128];
  __shared__ __align__(16) unsigned short vS[64 * 128];
  const float SC = 0.125f * 1.44269504088896f;

  b16x8 qf[4][2];   // B-frags of q (col=b=ln)
#pragma unroll
  for (int n = 0; n < 4; ++n)
#pragma unroll
    for (int ks = 0; ks < 2; ++ks) {
      int b = 64 * wc + 16 * n + ln;
      qf[n][ks] = *reinterpret_cast<const b16x8*>(&qb[(size_t)b * 512 + h * 64 + ks * 32 + g * 8]);
    }
  f32x4 pacc[2][4];
#pragma unroll
  for (int m = 0; m < 2; ++m)
#pragma unroll
    for (int n = 0; n < 4; ++n) pacc[m][n] = {0.f, 0.f, 0.f, 0.f};
  float lsum[4] = {0.f, 0.f, 0.f, 0.f};

  for (int it = 0; it < 8; ++it) {
    int c0g = cg * 1024 + it * 128;
#pragma unroll
    for (int i = 0; i < 4; ++i) {
      int fl = i * 256 + tid, row = fl >> 3, p8 = fl & 7;
      uint4 d = *reinterpret_cast<const uint4*>(&kb[(size_t)(c0g + row) * 512 + h * 64 + p8 * 8]);
      *reinterpret_cast<uint4*>(&kS[(row * 8 + (p8 ^ (row & 7))) * 8]) = d;
    }
#pragma unroll
    for (int i = 0; i < 4; ++i) {
      int fl = i * 256 + tid, row = fl >> 4, p16 = fl & 15;
      uint4 d = *reinterpret_cast<const uint4*>(&vt[(size_t)(h * 64 + row) * 65536 + c0g + p16 * 8]);
      *reinterpret_cast<uint4*>(&vS[(row * 16 + (p16 ^ (row & 7))) * 8]) = d;
    }
    __syncthreads();

    f32x4 sacc[4][4];
#pragma unroll
    for (int m = 0; m < 4; ++m)
#pragma unroll
      for (int n = 0; n < 4; ++n) sacc[m][n] = {0.f, 0.f, 0.f, 0.f};
#pragma unroll
    for (int ks = 0; ks < 2; ++ks) {
      b16x8 a[4];
#pragma unroll
      for (int m = 0; m < 4; ++m) {
        int row = 64 * wr + 16 * m + ln;
        a[m] = *reinterpret_cast<const b16x8*>(&kS[(row * 8 + ((ks * 4 + g) ^ (row & 7))) * 8]);
      }
#pragma unroll
      for (int m = 0; m < 4; ++m)
#pragma unroll
        for (int n = 0; n < 4; ++n) sacc[m][n] = MFMA(a[m], qf[n][ks], sacc[m][n]);
    }
#pragma unroll
    for (int m = 0; m < 4; ++m)
#pragma unroll
      for (int n = 0; n < 4; ++n) {
        float p0 = __builtin_amdgcn_exp2f(sacc[m][n][0] * SC);
        float p1 = __builtin_amdgcn_exp2f(sacc[m][n][1] * SC);
        float p2 = __builtin_amdgcn_exp2f(sacc[m][n][2] * SC);
        float p3 = __builtin_amdgcn_exp2f(sacc[m][n][3] * SC);
        lsum[n] += (p0 + p1) + (p2 + p3);
        int b = 64 * wc + 16 * n + ln;
        int c = 64 * wr + 16 * m + 4 * g;
        int base = b * 128 + (((c >> 3) ^ (b & 7)) * 8) + (c & 7);
        ushort2 lo, hi;
        lo.x = f2bf(p0); lo.y = f2bf(p1);
        hi.x = f2bf(p2); hi.y = f2bf(p3);
        *reinterpret_cast<ushort2*>(&pS[base]) = lo;
        *reinterpret_cast<ushort2*>(&pS[base + 2]) = hi;
      }
    __syncthreads();
#pragma unroll
    for (int ks = 0; ks < 4; ++ks) {
      b16x8 av[2], bp[4];
#pragma unroll
      for (int m = 0; m < 2; ++m) {
        int row = 32 * wr + 16 * m + ln;
        av[m] = *reinterpret_cast<const b16x8*>(&vS[(row * 16 + ((ks * 4 + g) ^ (row & 7))) * 8]);
      }
#pragma unroll
      for (int n = 0; n < 4; ++n) {
        int row = 64 * wc + 16 * n + ln;
        bp[n] = *reinterpret_cast<const b16x8*>(&pS[(row * 16 + ((ks * 4 + g) ^ (row & 7))) * 8]);
      }
#pragma unroll
      for (int m = 0; m < 2; ++m)
#pragma unroll
        for (int n = 0; n < 4; ++n) pacc[m][n] = MFMA(av[m], bp[n], pacc[m][n]);
    }
    __syncthreads();
  }
#pragma unroll
  for (int n = 0; n < 4; ++n) {
    float v = lsum[n];
    v += __shfl_xor(v, 16, 64);
    v += __shfl_xor(v, 32, 64);
    if ((tid & 63) < 16) atomicAdd(&l_ws[h * 128 + 64 * wc + 16 * n + ln], v);
  }
#pragma unroll
  for (int m = 0; m < 2; ++m)
#pragma unroll
    for (int n = 0; n < 4; ++n)
#pragma unroll
      for (int r = 0; r < 4; ++r) {
        int d = 32 * wr + 16 * m + 4 * g + r;
        int b = 64 * wc + 16 * n + ln;
        atomicAdd(&ctxT[(h * 64 + d) * 128 + b], pacc[m][n][r]);
      }
}

// ---------------------------------------------------------------------------
// 6) attn2: recompute scores, avgA[c] += sum_b exp2(s*SC)/l[b,h]
__global__ __launch_bounds__(256) void k_attn2(
    const unsigned short* __restrict__ kb, const unsigned short* __restrict__ qb,
    const float* __restrict__ l_ws, float* __restrict__ avgA) {
  const int h = blockIdx.y, cg = blockIdx.x;
  const int tid = threadIdx.x;
  const int wv = tid >> 6, wr = wv >> 1, wc = wv & 1;
  const int ln = tid & 15, g = (tid & 63) >> 4;
  __shared__ __align__(16) unsigned short kS[128 * 64];
  __shared__ float wS[128];
  const float SC = 0.125f * 1.44269504088896f;
  if (tid < 128) wS[tid] = 1.f / l_ws[h * 128 + tid];
  b16x8 qf[4][2];
#pragma unroll
  for (int n = 0; n < 4; ++n)
#pragma unroll
    for (int ks = 0; ks < 2; ++ks) {
      int b = 64 * wc + 16 * n + ln;
      qf[n][ks] = *reinterpret_cast<const b16x8*>(&qb[(size_t)b * 512 + h * 64 + ks * 32 + g * 8]);
    }
  __syncthreads();
  float wn[4];
#pragma unroll
  for (int n = 0; n < 4; ++n) wn[n] = wS[64 * wc + 16 * n + ln];

  for (int it = 0; it < 8; ++it) {
    int c0g = cg * 1024 + it * 128;
#pragma unroll
    for (int i = 0; i < 4; ++i) {
      int fl = i * 256 + tid, row = fl >> 3, p8 = fl & 7;
      uint4 d = *reinterpret_cast<const uint4*>(&kb[(size_t)(c0g + row) * 512 + h * 64 + p8 * 8]);
      *reinterpret_cast<uint4*>(&kS[(row * 8 + (p8 ^ (row & 7))) * 8]) = d;
    }
    __syncthreads();
    f32x4 sacc[4][4];
#pragma unroll
    for (int m = 0; m < 4; ++m)
#pragma unroll
      for (int n = 0; n < 4; ++n) sacc[m][n] = {0.f, 0.f, 0.f, 0.f};
#pragma unroll
    for (int ks = 0; ks < 2; ++ks) {
      b16x8 a[4];
#pragma unroll
      for (int m = 0; m < 4; ++m) {
        int row = 64 * wr + 16 * m + ln;
        a[m] = *reinterpret_cast<const b16x8*>(&kS[(row * 8 + ((ks * 4 + g) ^ (row & 7))) * 8]);
      }
#pragma unroll
      for (int m = 0; m < 4; ++m)
#pragma unroll
        for (int n = 0; n < 4; ++n) sacc[m][n] = MFMA(a[m], qf[n][ks], sacc[m][n]);
    }
#pragma unroll
    for (int m = 0; m < 4; ++m) {
      float s0 = 0.f, s1 = 0.f, s2 = 0.f, s3 = 0.f;
#pragma unroll
      for (int n = 0; n < 4; ++n) {
        s0 += __builtin_amdgcn_exp2f(sacc[m][n][0] * SC) * wn[n];
        s1 += __builtin_amdgcn_exp2f(sacc[m][n][1] * SC) * wn[n];
        s2 += __builtin_amdgcn_exp2f(sacc[m][n][2] * SC) * wn[n];
        s3 += __builtin_amdgcn_exp2f(sacc[m][n][3] * SC) * wn[n];
      }
#pragma unroll
      for (int off = 1; off < 16; off <<= 1) {
        s0 += __shfl_xor(s0, off, 64);
        s1 += __shfl_xor(s1, off, 64);
        s2 += __shfl_xor(s2, off, 64);
        s3 += __shfl_xor(s3, off, 64);
      }
      if (ln == 0) {
        int c = c0g + 64 * wr + 16 * m + 4 * g;
        atomicAdd(&avgA[c], s0);
        atomicAdd(&avgA[c + 1], s1);
        atomicAdd(&avgA[c + 2], s2);
        atomicAdd(&avgA[c + 3], s3);
      }
    }
    __syncthreads();
  }
}

// ---------------------------------------------------------------------------
// 7) finalize: ctx = ctxT/l, attn_out = ctx·Wout^T + bo, out = gate*attn_out
__global__ void k_finalize(const float* __restrict__ ctxT, const float* __restrict__ l_ws,
                           const float* __restrict__ wout, const float* __restrict__ bout,
                           const float* __restrict__ gate, float* __restrict__ out) {
  __shared__ float cs[512];
  int b = blockIdx.x, j = threadIdx.x;                 // 512 threads
  cs[j] = ctxT[j * 128 + b] / l_ws[(j >> 6) * 128 + b];
  __syncthreads();
  float acc = bout[j];
  const float4* c4 = reinterpret_cast<const float4*>(cs);
  const float4* w4 = reinterpret_cast<const float4*>(wout + j * 512);
#pragma unroll 8
  for (int i = 0; i < 128; ++i) {
    float4 a = c4[i], c = w4[i];
    acc += a.x * c.x + a.y * c.y + a.z * c.z + a.w * c.w;
  }
  out[b * 512 + j] = gate[b] * acc;
}

// ---------------------------------------------------------------------------
// 8) usage/last outputs
__global__ void k_usage(const float* __restrict__ avgA, const float* __restrict__ usage,
                        const float* __restrict__ last, const int* __restrict__ step,
                        float* __restrict__ out_usage, float* __restrict__ out_last) {
  int c = blockIdx.x * 256 + threadIdx.x;
  float avg = avgA[c] * (1.f / 1024.f);
  out_usage[c] = usage[c] + avg;
  out_last[c] = (avg > 0.001f) ? (float)step[0] : last[c];
}

// ---------------------------------------------------------------------------
extern "C" void kernel_launch(void* const* d_in, const int* in_sizes, int n_in,
                              void* d_out, int out_size, void* d_ws, size_t ws_size,
                              hipStream_t stream) {
  const float* query = (const float*)d_in[0];
  const float* mk    = (const float*)d_in[1];
  const float* mv    = (const float*)d_in[2];
  const float* in_w  = (const float*)d_in[3];
  const float* in_b  = (const float*)d_in[4];
  const float* out_w = (const float*)d_in[5];
  const float* out_b = (const float*)d_in[6];
  const float* gw1   = (const float*)d_in[7];
  const float* gb1   = (const float*)d_in[8];
  const float* gw2   = (const float*)d_in[9];
  const float* gb2   = (const float*)d_in[10];
  const float* usage = (const float*)d_in[11];
  const float* last  = (const float*)d_in[12];
  const int*   step  = (const int*)d_in[13];

  char* ws = (char*)d_ws;
  unsigned short* qb  = (unsigned short*)(ws);               // 131072 B
  unsigned short* wkb = (unsigned short*)(ws + 131072);      // 524288 B
  unsigned short* wvb = (unsigned short*)(ws + 655360);      // 524288 B
  unsigned short* kb  = (unsigned short*)(ws + 1179648);     // 64 MB (k bf16 [CAP][512])
  unsigned short* vt  = (unsigned short*)(ws + 68288512);    // 64 MB (vT bf16 [512][CAP])
  float* l_ws = (float*)(ws + 135397376);                    // 4 KB  [h][b]
  float* ctxT = (float*)(ws + 135401472);                    // 256 KB [h*64+d][b]
  float* avgA = (float*)(ws + 135663616);                    // 256 KB [c]
  float* gate = (float*)(ws + 135925760);                    // 512 B
  float* out = (float*)d_out;

  // zero accumulators (l_ws | ctxT | avgA are contiguous)
  hipMemsetAsync(ws + 135397376, 0, 4096 + 262144 + 262144, stream);

  k_convert_w<<<512, 256, 0, stream>>>(in_w, wkb);           // fills wkb+wvb
  k_proj_q<<<128, 512, 0, stream>>>(query, in_w, in_b, qb);
  k_gate<<<128, 128, 0, stream>>>(query, gw1, gb1, gw2, gb2, gate);
  k_proj_kv<<<2048, 512, 0, stream>>>(mk, mv, wkb, wvb, in_b, kb, vt);
  k_attn1<<<dim3(64, 8), 256, 0, stream>>>(kb, vt, qb, l_ws, ctxT);
  k_attn2<<<dim3(64, 8), 256, 0, stream>>>(kb, qb, l_ws, avgA);
  k_finalize<<<128, 512, 0, stream>>>(ctxT, l_ws, out_w, out_b, gate, out);
  k_usage<<<256, 256, 0, stream>>>(avgA, usage, last, step, out + 65536, out + 131072);
}

// Round 16
// 344.433 us; speedup vs baseline: 1.3552x; 1.3552x over previous
//
#include <hip/hip_runtime.h>
#include <stdint.h>

// Problem constants: B=128, CAP=65536, H=512, NH=8, HD=64, GH=128
// Outputs (f32): memory_output[128*512] | new_usage[65536] | new_last[65536]

typedef __bf16 b16x8 __attribute__((ext_vector_type(8)));
typedef float f32x4 __attribute__((ext_vector_type(4)));

static __device__ __forceinline__ unsigned short f2bf(float f) {
  return __builtin_bit_cast(unsigned short, (__bf16)f);   // compiler emits v_cvt_pk_bf16_f32
}

static __device__ __forceinline__ f32x4 MFMA(b16x8 a, b16x8 b, f32x4 c) {
  return __builtin_amdgcn_mfma_f32_16x16x32_bf16(a, b, c, 0, 0, 0);
}

#define GLL16(g, l)                                                          \
  __builtin_amdgcn_global_load_lds(                                          \
      (const __attribute__((address_space(1))) void*)(g),                    \
      (__attribute__((address_space(3))) void*)(l), 16, 0, 0)

#define SBAR() __builtin_amdgcn_sched_barrier(0)

// ---------------------------------------------------------------------------
// 1) convert wk,wv (in_proj_w rows 512..1535) fp32 -> bf16, contiguous dest
__global__ void k_convert_w(const float* __restrict__ w, unsigned short* __restrict__ dst) {
  int i = blockIdx.x * 256 + threadIdx.x;              // 131072 threads x 4 elems
  float4 v = reinterpret_cast<const float4*>(w + 512 * 512)[i];
  ushort4 o;
  o.x = f2bf(v.x); o.y = f2bf(v.y); o.z = f2bf(v.z); o.w = f2bf(v.w);
  reinterpret_cast<ushort4*>(dst)[i] = o;
}

// ---------------------------------------------------------------------------
// 2) q projection: q[b][j] = query[b,:]·wq[j,:] + bq[j]  (fp32 dot, bf16 out)
__global__ void k_proj_q(const float* __restrict__ query, const float* __restrict__ w,
                         const float* __restrict__ bias, unsigned short* __restrict__ qout) {
  __shared__ float qs[512];
  int b = blockIdx.x, j = threadIdx.x;                 // 512 threads
  qs[j] = query[b * 512 + j];
  __syncthreads();
  float acc = bias[j];
  const float4* q4 = reinterpret_cast<const float4*>(qs);
  const float4* w4 = reinterpret_cast<const float4*>(w + j * 512);
#pragma unroll 8
  for (int i = 0; i < 128; ++i) {
    float4 a = q4[i], c = w4[i];
    acc += a.x * c.x + a.y * c.y + a.z * c.z + a.w * c.w;
  }
  qout[b * 512 + j] = f2bf(acc);
}

// ---------------------------------------------------------------------------
// 3) gate[b] = sigmoid(relu(query·gw1^T + gb1)·gw2^T + gb2)
__global__ void k_gate(const float* __restrict__ query, const float* __restrict__ w1,
                       const float* __restrict__ b1, const float* __restrict__ w2,
                       const float* __restrict__ b2, float* __restrict__ gate) {
  __shared__ float qs[512];
  __shared__ float red[2];
  int b = blockIdx.x, j = threadIdx.x;                 // 128 threads
  qs[j] = query[b * 512 + j];
  qs[j + 128] = query[b * 512 + j + 128];
  qs[j + 256] = query[b * 512 + j + 256];
  qs[j + 384] = query[b * 512 + j + 384];
  __syncthreads();
  float acc = b1[j];
  const float4* q4 = reinterpret_cast<const float4*>(qs);
  const float4* w4 = reinterpret_cast<const float4*>(w1 + j * 512);
#pragma unroll 8
  for (int i = 0; i < 128; ++i) {
    float4 a = q4[i], c = w4[i];
    acc += a.x * c.x + a.y * c.y + a.z * c.z + a.w * c.w;
  }
  float t = fmaxf(acc, 0.f) * w2[j];
#pragma unroll
  for (int off = 1; off < 64; off <<= 1) t += __shfl_xor(t, off, 64);
  if ((j & 63) == 0) red[j >> 6] = t;
  __syncthreads();
  if (j == 0) {
    float z = red[0] + red[1] + b2[0];
    gate[b] = 1.f / (1.f + __builtin_amdgcn_exp2f(-z * 1.44269504088896f));
  }
}

// ---------------------------------------------------------------------------
// 4) K/V projection GEMMs — A-RESIDENT BM=64 (R13 best-known config).
//    A (64 rows x K=512 bf16, chunk^(row&7)) staged once: 64 KB. W ring-2
//    [128 j][32 K] = 2x8 KB via GLL (2/thread/step, chunk^((row>>1)&3)).
//    Race-safe lockstep: counted vmcnt(2) + 2 barriers/step. LDS=80 KB.
//    256 thr / 4 waves, wave w owns j-slice [32w,+32): acc[4][2], 8 MFMA/step.
__global__ __launch_bounds__(256, 2) void k_proj_kv(
    const float* __restrict__ mk, const float* __restrict__ mv,
    const unsigned short* __restrict__ wkb, const unsigned short* __restrict__ wvb,
    const float* __restrict__ in_b,
    unsigned short* __restrict__ kout, unsigned short* __restrict__ vtout) {
  const int p = blockIdx.x;                            // 2048 blocks
  const int isV = p & 1;
  const int c0 = (p >> 1) * 64;
  const float* Ag = isV ? mv : mk;
  const unsigned short* W = isV ? wvb : wkb;
  const float* bias = in_b + (isV ? 1024 : 512);
  const int tid = threadIdx.x;
  const int w = tid >> 6, lane = tid & 63;             // wave grid 1 (c) x 4 (j)
  const int ln = tid & 15, g = (tid & 63) >> 4;

  __shared__ __align__(16) unsigned short AL[32768];   // 64 KB [64][512] bf16 swz
  __shared__ __align__(16) unsigned short WL[2][4096]; // 16 KB ring [128 j][32 K]

  // W staging: 2 GLL/thread/step. GLL i covers rows i*64 + 16w + (lane>>2);
  // source chunk pre-swizzled cs = (lane&3) ^ ((row>>1)&3)  (same for i=0,1).
  const int srow = 16 * w + (lane >> 2);               // 0..63
  const int csrc = (lane & 3) ^ ((srow >> 1) & 3);
  const int wd0 = w * 512;                             // ushort idx (+lane*16B HW)
  const int wd1 = 2048 + w * 512;

  // --- prologue: issue W(t=0) so latency overlaps the A-stage ---
  GLL16(W + (size_t)srow * 512 + csrc * 8, &WL[0][wd0]);
  GLL16(W + (size_t)(64 + srow) * 512 + csrc * 8, &WL[0][wd1]);

  // --- A-stage: 16 iters, wave w reads full 2-KB row (c*4+w), cvt, swz write
#pragma unroll 4
  for (int c = 0; c < 16; ++c) {
    int row = c * 4 + w;
    const float* src = Ag + (size_t)(c0 + row) * 512 + lane * 8;
    float4 f0 = *reinterpret_cast<const float4*>(src);
    float4 f1 = *reinterpret_cast<const float4*>(src + 4);
    b16x8 v;
    v[0] = (__bf16)f0.x; v[1] = (__bf16)f0.y; v[2] = (__bf16)f0.z; v[3] = (__bf16)f0.w;
    v[4] = (__bf16)f1.x; v[5] = (__bf16)f1.y; v[6] = (__bf16)f1.z; v[7] = (__bf16)f1.w;
    int chunk = lane ^ (row & 7);                      // 16-B chunk swizzle
    *reinterpret_cast<b16x8*>(&AL[row * 512 + chunk * 8]) = v;
  }
  __syncthreads();                                     // A visible; W(0) landed

  // --- main loop: 4 j-tiles x 16 K-steps (BK=32), race-safe lockstep ---
#pragma unroll
  for (int jt = 0; jt < 4; ++jt) {
    f32x4 acc[4][2];
#pragma unroll
    for (int m = 0; m < 4; ++m)
#pragma unroll
      for (int n = 0; n < 2; ++n) acc[m][n] = {0.f, 0.f, 0.f, 0.f};

#pragma unroll
    for (int kk = 0; kk < 16; ++kk) {
      const int t = jt * 16 + kk;
      const int tn = (t < 63) ? t + 1 : 63;            // clamped tail (dup, same bytes)
      const int jn = tn >> 4, kn = tn & 15, sl = tn & 1;
      // issue W(t+1): slot released by end-of-step barrier of t-1
      GLL16(W + (size_t)(jn * 128 + srow) * 512 + kn * 32 + csrc * 8, &WL[sl][wd0]);
      GLL16(W + (size_t)(jn * 128 + 64 + srow) * 512 + kn * 32 + csrc * 8, &WL[sl][wd1]);
      SBAR();
      asm volatile("s_waitcnt vmcnt(2)" ::: "memory"); // W(t) landed; W(t+1) in flight
      SBAR();
      __builtin_amdgcn_s_barrier();                    // all waves: W(t) visible
      SBAR();
      // fragments: A 4x b128, W 2x b128 (2-way bank = free)
      b16x8 af[4], wf[2];
#pragma unroll
      for (int m = 0; m < 4; ++m) {
        int r = 16 * m + ln;
        int ch = (kk * 4 + g) ^ (r & 7);
        af[m] = *reinterpret_cast<const b16x8*>(&AL[r * 512 + ch * 8]);
      }
#pragma unroll
      for (int n = 0; n < 2; ++n) {
        int r = 32 * w + 16 * n + ln;
        int ch = g ^ ((r >> 1) & 3);
        wf[n] = *reinterpret_cast<const b16x8*>(&WL[t & 1][r * 32 + ch * 8]);
      }
      if (!isV) {
#pragma unroll
        for (int m = 0; m < 4; ++m)
#pragma unroll
          for (int n = 0; n < 2; ++n) acc[m][n] = MFMA(wf[n], af[m], acc[m][n]);
      } else {
#pragma unroll
        for (int m = 0; m < 4; ++m)
#pragma unroll
          for (int n = 0; n < 2; ++n) acc[m][n] = MFMA(af[m], wf[n], acc[m][n]);
      }
      SBAR();
      __builtin_amdgcn_s_barrier();                    // release slot t&1
      SBAR();
    }

    // epilogue for this j-tile (verified mapping, wr=0, wc=w)
    const int j0 = jt * 128;
    if (!isV) {
#pragma unroll
      for (int m = 0; m < 4; ++m) {
        int c = c0 + 16 * m + ln;
#pragma unroll
        for (int n = 0; n < 2; ++n) {
          int jb = j0 + 32 * w + 16 * n + 4 * g;
          float4 bb = *reinterpret_cast<const float4*>(&bias[jb]);
          ushort4 o;
          o.x = f2bf(acc[m][n][0] + bb.x);
          o.y = f2bf(acc[m][n][1] + bb.y);
          o.z = f2bf(acc[m][n][2] + bb.z);
          o.w = f2bf(acc[m][n][3] + bb.w);
          *reinterpret_cast<ushort4*>(&kout[(size_t)c * 512 + jb]) = o;
        }
      }
    } else {
#pragma unroll
      for (int n = 0; n < 2; ++n) {
        int j = j0 + 32 * w + 16 * n + ln;
        float bj = bias[j];
#pragma unroll
        for (int m = 0; m < 4; ++m) {
          int cb = c0 + 16 * m + 4 * g;
          ushort4 o;
          o.x = f2bf(acc[m][n][0] + bj);
          o.y = f2bf(acc[m][n][1] + bj);
          o.z = f2bf(acc[m][n][2] + bj);
          o.w = f2bf(acc[m][n][3] + bj);
          *reinterpret_cast<ushort4*>(&vtout[(size_t)j * 65536 + cb]) = o;
        }
      }
    }
  }
  asm volatile("s_waitcnt vmcnt(0)" ::: "memory");     // retire dup tail GLLs
}

// ---------------------------------------------------------------------------
// 5) attn1: per (head, c-group of 1024): sT = k·q^T (swapped QK^T), p=exp2(s*SC),
//    l[b,h] += row sums; ctxT[h*64+d][b] += sum_c p·vT  (unnormalized)
__global__ __launch_bounds__(256) void k_attn1(
    const unsigned short* __restrict__ kb, const unsigned short* __restrict__ vt,
    const unsigned short* __restrict__ qb,
    float* __restrict__ l_ws, float* __restrict__ ctxT) {
  const int h = blockIdx.y, cg = blockIdx.x;
  const int tid = threadIdx.x;
  const int wv = tid >> 6, wr = wv >> 1, wc = wv & 1;
  const int ln = tid & 15, g = (tid & 63) >> 4;
  __shared__ __align__(16) unsigned short kS[128 * 64];
  __shared__ __align__(16) unsigned short pS[128 * 128];
  __shared__ __align__(16) unsigned short vS[64 * 128];
  const float SC = 0.125f * 1.44269504088896f;

  b16x8 qf[4][2];   // B-frags of q (col=b=ln)
#pragma unroll
  for (int n = 0; n < 4; ++n)
#pragma unroll
    for (int ks = 0; ks < 2; ++ks) {
      int b = 64 * wc + 16 * n + ln;
      qf[n][ks] = *reinterpret_cast<const b16x8*>(&qb[(size_t)b * 512 + h * 64 + ks * 32 + g * 8]);
    }
  f32x4 pacc[2][4];
#pragma unroll
  for (int m = 0; m < 2; ++m)
#pragma unroll
    for (int n = 0; n < 4; ++n) pacc[m][n] = {0.f, 0.f, 0.f, 0.f};
  float lsum[4] = {0.f, 0.f, 0.f, 0.f};

  for (int it = 0; it < 8; ++it) {
    int c0g = cg * 1024 + it * 128;
#pragma unroll
    for (int i = 0; i < 4; ++i) {
      int fl = i * 256 + tid, row = fl >> 3, p8 = fl & 7;
      uint4 d = *reinterpret_cast<const uint4*>(&kb[(size_t)(c0g + row) * 512 + h * 64 + p8 * 8]);
      *reinterpret_cast<uint4*>(&kS[(row * 8 + (p8 ^ (row & 7))) * 8]) = d;
    }
#pragma unroll
    for (int i = 0; i < 4; ++i) {
      int fl = i * 256 + tid, row = fl >> 4, p16 = fl & 15;
      uint4 d = *reinterpret_cast<const uint4*>(&vt[(size_t)(h * 64 + row) * 65536 + c0g + p16 * 8]);
      *reinterpret_cast<uint4*>(&vS[(row * 16 + (p16 ^ (row & 7))) * 8]) = d;
    }
    __syncthreads();

    f32x4 sacc[4][4];
#pragma unroll
    for (int m = 0; m < 4; ++m)
#pragma unroll
      for (int n = 0; n < 4; ++n) sacc[m][n] = {0.f, 0.f, 0.f, 0.f};
#pragma unroll
    for (int ks = 0; ks < 2; ++ks) {
      b16x8 a[4];
#pragma unroll
      for (int m = 0; m < 4; ++m) {
        int row = 64 * wr + 16 * m + ln;
        a[m] = *reinterpret_cast<const b16x8*>(&kS[(row * 8 + ((ks * 4 + g) ^ (row & 7))) * 8]);
      }
#pragma unroll
      for (int m = 0; m < 4; ++m)
#pragma unroll
        for (int n = 0; n < 4; ++n) sacc[m][n] = MFMA(a[m], qf[n][ks], sacc[m][n]);
    }
#pragma unroll
    for (int m = 0; m < 4; ++m)
#pragma unroll
      for (int n = 0; n < 4; ++n) {
        float p0 = __builtin_amdgcn_exp2f(sacc[m][n][0] * SC);
        float p1 = __builtin_amdgcn_exp2f(sacc[m][n][1] * SC);
        float p2 = __builtin_amdgcn_exp2f(sacc[m][n][2] * SC);
        float p3 = __builtin_amdgcn_exp2f(sacc[m][n][3] * SC);
        lsum[n] += (p0 + p1) + (p2 + p3);
        int b = 64 * wc + 16 * n + ln;
        int c = 64 * wr + 16 * m + 4 * g;
        int base = b * 128 + (((c >> 3) ^ (b & 7)) * 8) + (c & 7);
        ushort2 lo, hi;
        lo.x = f2bf(p0); lo.y = f2bf(p1);
        hi.x = f2bf(p2); hi.y = f2bf(p3);
        *reinterpret_cast<ushort2*>(&pS[base]) = lo;
        *reinterpret_cast<ushort2*>(&pS[base + 2]) = hi;
      }
    __syncthreads();
#pragma unroll
    for (int ks = 0; ks < 4; ++ks) {
      b16x8 av[2], bp[4];
#pragma unroll
      for (int m = 0; m < 2; ++m) {
        int row = 32 * wr + 16 * m + ln;
        av[m] = *reinterpret_cast<const b16x8*>(&vS[(row * 16 + ((ks * 4 + g) ^ (row & 7))) * 8]);
      }
#pragma unroll
      for (int n = 0; n < 4; ++n) {
        int row = 64 * wc + 16 * n + ln;
        bp[n] = *reinterpret_cast<const b16x8*>(&pS[(row * 16 + ((ks * 4 + g) ^ (row & 7))) * 8]);
      }
#pragma unroll
      for (int m = 0; m < 2; ++m)
#pragma unroll
        for (int n = 0; n < 4; ++n) pacc[m][n] = MFMA(av[m], bp[n], pacc[m][n]);
    }
    __syncthreads();
  }
#pragma unroll
  for (int n = 0; n < 4; ++n) {
    float v = lsum[n];
    v += __shfl_xor(v, 16, 64);
    v += __shfl_xor(v, 32, 64);
    if ((tid & 63) < 16) atomicAdd(&l_ws[h * 128 + 64 * wc + 16 * n + ln], v);
  }
#pragma unroll
  for (int m = 0; m < 2; ++m)
#pragma unroll
    for (int n = 0; n < 4; ++n)
#pragma unroll
      for (int r = 0; r < 4; ++r) {
        int d = 32 * wr + 16 * m + 4 * g + r;
        int b = 64 * wc + 16 * n + ln;
        atomicAdd(&ctxT[(h * 64 + d) * 128 + b], pacc[m][n][r]);
      }
}

// ---------------------------------------------------------------------------
// 6) attn2: recompute scores, avgA[c] += sum_b exp2(s*SC)/l[b,h]
__global__ __launch_bounds__(256) void k_attn2(
    const unsigned short* __restrict__ kb, const unsigned short* __restrict__ qb,
    const float* __restrict__ l_ws, float* __restrict__ avgA) {
  const int h = blockIdx.y, cg = blockIdx.x;
  const int tid = threadIdx.x;
  const int wv = tid >> 6, wr = wv >> 1, wc = wv & 1;
  const int ln = tid & 15, g = (tid & 63) >> 4;
  __shared__ __align__(16) unsigned short kS[128 * 64];
  __shared__ float wS[128];
  const float SC = 0.125f * 1.44269504088896f;
  if (tid < 128) wS[tid] = 1.f / l_ws[h * 128 + tid];
  b16x8 qf[4][2];
#pragma unroll
  for (int n = 0; n < 4; ++n)
#pragma unroll
    for (int ks = 0; ks < 2; ++ks) {
      int b = 64 * wc + 16 * n + ln;
      qf[n][ks] = *reinterpret_cast<const b16x8*>(&qb[(size_t)b * 512 + h * 64 + ks * 32 + g * 8]);
    }
  __syncthreads();
  float wn[4];
#pragma unroll
  for (int n = 0; n < 4; ++n) wn[n] = wS[64 * wc + 16 * n + ln];

  for (int it = 0; it < 8; ++it) {
    int c0g = cg * 1024 + it * 128;
#pragma unroll
    for (int i = 0; i < 4; ++i) {
      int fl = i * 256 + tid, row = fl >> 3, p8 = fl & 7;
      uint4 d = *reinterpret_cast<const uint4*>(&kb[(size_t)(c0g + row) * 512 + h * 64 + p8 * 8]);
      *reinterpret_cast<uint4*>(&kS[(row * 8 + (p8 ^ (row & 7))) * 8]) = d;
    }
    __syncthreads();
    f32x4 sacc[4][4];
#pragma unroll
    for (int m = 0; m < 4; ++m)
#pragma unroll
      for (int n = 0; n < 4; ++n) sacc[m][n] = {0.f, 0.f, 0.f, 0.f};
#pragma unroll
    for (int ks = 0; ks < 2; ++ks) {
      b16x8 a[4];
#pragma unroll
      for (int m = 0; m < 4; ++m) {
        int row = 64 * wr + 16 * m + ln;
        a[m] = *reinterpret_cast<const b16x8*>(&kS[(row * 8 + ((ks * 4 + g) ^ (row & 7))) * 8]);
      }
#pragma unroll
      for (int m = 0; m < 4; ++m)
#pragma unroll
        for (int n = 0; n < 4; ++n) sacc[m][n] = MFMA(a[m], qf[n][ks], sacc[m][n]);
    }
#pragma unroll
    for (int m = 0; m < 4; ++m) {
      float s0 = 0.f, s1 = 0.f, s2 = 0.f, s3 = 0.f;
#pragma unroll
      for (int n = 0; n < 4; ++n) {
        s0 += __builtin_amdgcn_exp2f(sacc[m][n][0] * SC) * wn[n];
        s1 += __builtin_amdgcn_exp2f(sacc[m][n][1] * SC) * wn[n];
        s2 += __builtin_amdgcn_exp2f(sacc[m][n][2] * SC) * wn[n];
        s3 += __builtin_amdgcn_exp2f(sacc[m][n][3] * SC) * wn[n];
      }
#pragma unroll
      for (int off = 1; off < 16; off <<= 1) {
        s0 += __shfl_xor(s0, off, 64);
        s1 += __shfl_xor(s1, off, 64);
        s2 += __shfl_xor(s2, off, 64);
        s3 += __shfl_xor(s3, off, 64);
      }
      if (ln == 0) {
        int c = c0g + 64 * wr + 16 * m + 4 * g;
        atomicAdd(&avgA[c], s0);
        atomicAdd(&avgA[c + 1], s1);
        atomicAdd(&avgA[c + 2], s2);
        atomicAdd(&avgA[c + 3], s3);
      }
    }
    __syncthreads();
  }
}

// ---------------------------------------------------------------------------
// 7) finalize: ctx = ctxT/l, attn_out = ctx·Wout^T + bo, out = gate*attn_out
__global__ void k_finalize(const float* __restrict__ ctxT, const float* __restrict__ l_ws,
                           const float* __restrict__ wout, const float* __restrict__ bout,
                           const float* __restrict__ gate, float* __restrict__ out) {
  __shared__ float cs[512];
  int b = blockIdx.x, j = threadIdx.x;                 // 512 threads
  cs[j] = ctxT[j * 128 + b] / l_ws[(j >> 6) * 128 + b];
  __syncthreads();
  float acc = bout[j];
  const float4* c4 = reinterpret_cast<const float4*>(cs);
  const float4* w4 = reinterpret_cast<const float4*>(wout + j * 512);
#pragma unroll 8
  for (int i = 0; i < 128; ++i) {
    float4 a = c4[i], c = w4[i];
    acc += a.x * c.x + a.y * c.y + a.z * c.z + a.w * c.w;
  }
  out[b * 512 + j] = gate[b] * acc;
}

// ---------------------------------------------------------------------------
// 8) usage/last outputs
__global__ void k_usage(const float* __restrict__ avgA, const float* __restrict__ usage,
                        const float* __restrict__ last, const int* __restrict__ step,
                        float* __restrict__ out_usage, float* __restrict__ out_last) {
  int c = blockIdx.x * 256 + threadIdx.x;
  float avg = avgA[c] * (1.f / 1024.f);
  out_usage[c] = usage[c] + avg;
  out_last[c] = (avg > 0.001f) ? (float)step[0] : last[c];
}

// ---------------------------------------------------------------------------
extern "C" void kernel_launch(void* const* d_in, const int* in_sizes, int n_in,
                              void* d_out, int out_size, void* d_ws, size_t ws_size,
                              hipStream_t stream) {
  const float* query = (const float*)d_in[0];
  const float* mk    = (const float*)d_in[1];
  const float* mv    = (const float*)d_in[2];
  const float* in_w  = (const float*)d_in[3];
  const float* in_b  = (const float*)d_in[4];
  const float* out_w = (const float*)d_in[5];
  const float* out_b = (const float*)d_in[6];
  const float* gw1   = (const float*)d_in[7];
  const float* gb1   = (const float*)d_in[8];
  const float* gw2   = (const float*)d_in[9];
  const float* gb2   = (const float*)d_in[10];
  const float* usage = (const float*)d_in[11];
  const float* last  = (const float*)d_in[12];
  const int*   step  = (const int*)d_in[13];

  char* ws = (char*)d_ws;
  unsigned short* qb  = (unsigned short*)(ws);               // 131072 B
  unsigned short* wkb = (unsigned short*)(ws + 131072);      // 524288 B
  unsigned short* wvb = (unsigned short*)(ws + 655360);      // 524288 B
  unsigned short* kb  = (unsigned short*)(ws + 1179648);     // 64 MB (k bf16 [CAP][512])
  unsigned short* vt  = (unsigned short*)(ws + 68288512);    // 64 MB (vT bf16 [512][CAP])
  float* l_ws = (float*)(ws + 135397376);                    // 4 KB  [h][b]
  float* ctxT = (float*)(ws + 135401472);                    // 256 KB [h*64+d][b]
  float* avgA = (float*)(ws + 135663616);                    // 256 KB [c]
  float* gate = (float*)(ws + 135925760);                    // 512 B
  float* out = (float*)d_out;

  // zero accumulators (l_ws | ctxT | avgA are contiguous)
  hipMemsetAsync(ws + 135397376, 0, 4096 + 262144 + 262144, stream);

  k_convert_w<<<512, 256, 0, stream>>>(in_w, wkb);           // fills wkb+wvb
  k_proj_q<<<128, 512, 0, stream>>>(query, in_w, in_b, qb);
  k_gate<<<128, 128, 0, stream>>>(query, gw1, gb1, gw2, gb2, gate);
  k_proj_kv<<<2048, 256, 0, stream>>>(mk, mv, wkb, wvb, in_b, kb, vt);
  k_attn1<<<dim3(64, 8), 256, 0, stream>>>(kb, vt, qb, l_ws, ctxT);
  k_attn2<<<dim3(64, 8), 256, 0, stream>>>(kb, qb, l_ws, avgA);
  k_finalize<<<128, 512, 0, stream>>>(ctxT, l_ws, out_w, out_b, gate, out);
  k_usage<<<256, 256, 0, stream>>>(avgA, usage, last, step, out + 65536, out + 131072);
}